// Round 6
// baseline (5851.062 us; speedup 1.0000x reference)
//
#include <hip/hip_runtime.h>
#include <hip/hip_bf16.h>
#include <cstdint>

#define DEV __device__ __forceinline__

typedef unsigned short ushort;
typedef __attribute__((ext_vector_type(8))) short bf16x8;
typedef __attribute__((ext_vector_type(4))) float f32x4;

DEV float fsig(float x) { return 1.f / (1.f + __expf(-x)); }
DEV float ftanh(float x) { return 1.f - 2.f / (1.f + __expf(2.f * x)); }
DEV ushort f2bu(float f) {
  __hip_bfloat16 h = __float2bfloat16(f);
  return *(ushort*)&h;
}
DEV float b2f(ushort u) { return __uint_as_float((uint32_t)u << 16); }

// DPP butterfly add within TPU-sized groups (no DS pipe).
template <int CTRL>
DEV float dpp_add(float v) {
  int x = __builtin_amdgcn_update_dpp(0, __float_as_int(v), CTRL, 0xF, 0xF, true);
  return v + __int_as_float(x);
}
template <int TPU>
DEV float dpp_reduce(float v) {
  v = dpp_add<0xB1>(v);
  v = dpp_add<0x4E>(v);
  if (TPU >= 8) v = dpp_add<0x141>(v);
  if (TPU >= 16) v = dpp_add<0x140>(v);
  return v;
}

// Physical XCD id (hwreg 20 = HW_REG_XCC_ID on gfx940+; masked to 3 bits —
// any garbage value still lands in a valid bucket; protocol verifies).
DEV int get_xcd() {
  int x;
  asm volatile("s_getreg_b32 %0, hwreg(20, 0, 32)" : "=s"(x));
  return x & 7;
}

// sc0 = L1-bypass, L2-coherent (same-XCD fast path).
DEV void store_sc0_u32(uint32_t* p, uint32_t v) {
  asm volatile("global_store_dword %0, %1, off sc0" ::"v"(p), "v"(v) : "memory");
}
DEV uint32_t load_sc0_u32(const uint32_t* p) {
  uint32_t v;
  asm volatile("global_load_dword %0, %1, off sc0\ns_waitcnt vmcnt(0)"
               : "=v"(v) : "v"(p) : "memory");
  return v;
}
template <int PP>
DEV void fast_poll32(const uint32_t* p, uint32_t (&v)[PP]);
template <>
DEV void fast_poll32<4>(const uint32_t* p, uint32_t (&v)[4]) {
  asm volatile(
      "global_load_dword %0, %4, off sc0\n\t"
      "global_load_dword %1, %5, off sc0\n\t"
      "global_load_dword %2, %6, off sc0\n\t"
      "global_load_dword %3, %7, off sc0\n\t"
      "s_waitcnt vmcnt(0)"
      : "=&v"(v[0]), "=&v"(v[1]), "=&v"(v[2]), "=&v"(v[3])
      : "v"(p), "v"(p + 64), "v"(p + 128), "v"(p + 192)
      : "memory");
}
template <>
DEV void fast_poll32<8>(const uint32_t* p, uint32_t (&v)[8]) {
  asm volatile(
      "global_load_dword %0, %8, off sc0\n\t"
      "global_load_dword %1, %9, off sc0\n\t"
      "global_load_dword %2, %10, off sc0\n\t"
      "global_load_dword %3, %11, off sc0\n\t"
      "global_load_dword %4, %12, off sc0\n\t"
      "global_load_dword %5, %13, off sc0\n\t"
      "global_load_dword %6, %14, off sc0\n\t"
      "global_load_dword %7, %15, off sc0\n\t"
      "s_waitcnt vmcnt(0)"
      : "=&v"(v[0]), "=&v"(v[1]), "=&v"(v[2]), "=&v"(v[3]), "=&v"(v[4]),
        "=&v"(v[5]), "=&v"(v[6]), "=&v"(v[7])
      : "v"(p), "v"(p + 64), "v"(p + 128), "v"(p + 192), "v"(p + 256),
        "v"(p + 320), "v"(p + 384), "v"(p + 448)
      : "memory");
}

// ---------------------------------------------------------------------------
// MFMA bf16 GEMM: C[M,N](ldc) = act(A[M,K]_bf16 @ (BT[N,K]_bf16)^T + bias)
// flags: 1 = tanh, 2 = bf16 output. N%64==0, K%32==0; M guarded. bias nullable.
// ---------------------------------------------------------------------------
__global__ __launch_bounds__(256)
void mfma_gemm(const ushort* __restrict__ A, const ushort* __restrict__ BT,
               const float* __restrict__ bias, void* __restrict__ Cout,
               int M, int N, int K, int ldc, int flags) {
  const int wave = threadIdx.x >> 6, lane = threadIdx.x & 63;
  const int m0 = blockIdx.y * 64 + wave * 16;
  const int n0 = blockIdx.x * 64;
  const int r = lane & 15, quad = lane >> 4;
  f32x4 acc[4] = {};
  const int arow = (m0 + r < M) ? (m0 + r) : 0;
  const ushort* ap = A + (size_t)arow * K + quad * 8;
  const ushort* bp = BT + (size_t)(n0 + r) * K + quad * 8;
#pragma unroll 2
  for (int k0 = 0; k0 < K; k0 += 32) {
    bf16x8 a = *(const bf16x8*)(ap + k0);
#pragma unroll
    for (int t = 0; t < 4; ++t) {
      bf16x8 b = *(const bf16x8*)(bp + (size_t)t * 16 * K + k0);
      acc[t] = __builtin_amdgcn_mfma_f32_16x16x32_bf16(a, b, acc[t], 0, 0, 0);
    }
  }
#pragma unroll
  for (int t = 0; t < 4; ++t) {
    const int col = n0 + t * 16 + r;
    const float bs = bias ? bias[col] : 0.f;
#pragma unroll
    for (int e = 0; e < 4; ++e) {
      const int row = m0 + quad * 4 + e;
      if (row < M) {
        float v = acc[t][e] + bs;
        if (flags & 1) v = ftanh(v);
        if (flags & 2)
          ((ushort*)Cout)[(size_t)row * ldc + col] = f2bu(v);
        else
          ((float*)Cout)[(size_t)row * ldc + col] = v;
      }
    }
  }
}

// ---------------------------------------------------------------------------
// Batched transpose(+pad) prep: src fp32 [K][N] -> dst [N][Kp] (bf16 or fp32)
// ---------------------------------------------------------------------------
struct TDesc {
  const float* src;
  ushort* db;
  float* df;
  int K, N, Kp;
};
struct PrepArgs {
  TDesc d[19];
  int n;
};

__global__ __launch_bounds__(256)
void prep_kernel(PrepArgs pa) {
  int rem = blockIdx.x;
  int di = 0;
  TDesc d{};
  for (; di < pa.n; ++di) {
    d = pa.d[di];
    int t = ((d.N + 31) >> 5) * ((d.Kp + 31) >> 5);
    if (rem < t) break;
    rem -= t;
  }
  if (di == pa.n) return;
  const int ntx = (d.Kp + 31) >> 5;
  const int ty = rem / ntx, tx = rem % ntx;
  __shared__ float t32[32][33];
  const int lx = threadIdx.x & 31, ly = threadIdx.x >> 5;
#pragma unroll
  for (int p = 0; p < 4; ++p) {
    int k = tx * 32 + ly + 8 * p;
    int n = ty * 32 + lx;
    t32[ly + 8 * p][lx] = (k < d.K && n < d.N) ? d.src[(size_t)k * d.N + n] : 0.f;
  }
  __syncthreads();
#pragma unroll
  for (int p = 0; p < 4; ++p) {
    int n = ty * 32 + ly + 8 * p;
    int k = tx * 32 + lx;
    if (n < d.N && k < d.Kp) {
      float v = t32[lx][ly + 8 * p];
      if (d.df)
        d.df[(size_t)n * d.Kp + k] = v;
      else
        d.db[(size_t)n * d.Kp + k] = f2bu(v);
    }
  }
}

__global__ void cast_kernel(const float* __restrict__ in,
                            ushort* __restrict__ out, int n) {
  int i = (blockIdx.x * 256 + threadIdx.x) * 4;
  if (i + 3 < n) {
    float4 v = *(const float4*)(in + i);
    out[i] = f2bu(v.x);
    out[i + 1] = f2bu(v.y);
    out[i + 2] = f2bu(v.z);
    out[i + 3] = f2bu(v.w);
  }
}

__global__ void emb_kernel(const float* __restrict__ emb,
                           const int* __restrict__ text,
                           ushort* __restrict__ xe) {
  int s = blockIdx.x;
  int row = text[s];
  for (int k = threadIdx.x; k < 320; k += 256)
    xe[s * 320 + k] = (k < 300) ? f2bu(emb[(size_t)row * 300 + k]) : (ushort)0;
}

// ---------------------------------------------------------------------------
// Persistent multi-block GRU scan, v6: XCC_ID-verified same-XCD worker group.
// 256 blocks launched; workers = first W blocks registering on the winning
// XCD (pigeonhole: some XCD gets >= 32 of 256). Handshake empirically
// verifies sc0 (intra-L2) visibility; else falls back to agent/LLC protocol.
// Fast mode still dual-stores and slow-checks every 16 rounds (deadlock-free
// under any placement). Dedicated wave0 poller + LDS flag (R3 structure).
// ---------------------------------------------------------------------------
struct ScanDesc {
  const float* whhT;  // [3H][H]
  const float* bhh;   // [3H]
  const float* pre;   // [T][3H]
  float* out;         // out[pos*stride + off + unit] fp32
  ushort* outb;       // optional bf16 mirror
  ushort* outbT;      // optional bf16 transposed mirror [unit*tld + pos]
  uint32_t* hwS;      // [T][H] slow words (agent/LLC), zeroed per launch
  uint32_t* hwF;      // [T][H] fast words (sc0/L2), zeroed per launch
  int T, dir, stride, off, bstride, boff, tld;
};
struct ScanArgs {
  ScanDesc d[4];
  uint32_t* ctrl;  // 256 dwords, zeroed per launch
};

template <int H, int NB, int TPU, int NINST>
__global__ __launch_bounds__(256, 1)
void scan_kernel(ScanArgs args) {
  constexpr int UPB = H / NB;   // units per block
  constexpr int B = UPB * TPU;  // block threads (256)
  constexpr int KS = H / TPU;   // k elems per thread (32)
  constexpr int PP = H / 64;    // words per lane per poll
  constexpr int W = NB * NINST; // worker count (32)
  const int tid = threadIdx.x;

  __shared__ int sh_slot, sh_fast;
  if (tid == 0) {
    uint32_t* c = args.ctrl;
    const int x = get_xcd();
    int slot = (int)__hip_atomic_fetch_add(&c[x], 1u, __ATOMIC_RELAXED,
                                           __HIP_MEMORY_SCOPE_AGENT);
    if (slot == W - 1) atomicCAS((unsigned*)&c[8], 0u, (unsigned)(x + 1));
    unsigned win;
    while ((win = __hip_atomic_load(&c[8], __ATOMIC_RELAXED,
                                    __HIP_MEMORY_SCOPE_AGENT)) == 0) {}
    const bool work = ((int)win == x + 1) && slot < W;
    int fast = 0;
    if (work) {
      // publish tokens on both paths
      store_sc0_u32(&c[144 + slot], 0xC0FFEEu);
      __hip_atomic_store(&c[80 + slot], 1u, __ATOMIC_RELAXED,
                         __HIP_MEMORY_SCOPE_AGENT);
      // barrier: all W workers present (agent path — always correct)
      for (;;) {
        bool all = true;
#pragma unroll
        for (int i = 0; i < W; ++i)
          all = all && (__hip_atomic_load(&c[80 + i], __ATOMIC_RELAXED,
                                          __HIP_MEMORY_SCOPE_AGENT) != 0);
        if (all) break;
      }
      // bounded sc0 visibility probe
      int ok = 0;
      for (int r = 0; r < 128 && !ok; ++r) {
        bool all = true;
#pragma unroll
        for (int i = 0; i < W; ++i)
          all = all && (load_sc0_u32(&c[144 + i]) == 0xC0FFEEu);
        if (all) ok = 1;
      }
      __hip_atomic_store(&c[16 + slot], ok ? 1u : 2u, __ATOMIC_RELAXED,
                         __HIP_MEMORY_SCOPE_AGENT);
      if (slot == 0) {
        uint32_t g = 1;
        for (int i = 0; i < W; ++i) {
          uint32_t v;
          while ((v = __hip_atomic_load(&c[16 + i], __ATOMIC_RELAXED,
                                        __HIP_MEMORY_SCOPE_AGENT)) == 0) {}
          if (v != 1) g = 2;
        }
        __hip_atomic_store(&c[12], g, __ATOMIC_RELAXED,
                           __HIP_MEMORY_SCOPE_AGENT);
      }
      uint32_t g;
      while ((g = __hip_atomic_load(&c[12], __ATOMIC_RELAXED,
                                    __HIP_MEMORY_SCOPE_AGENT)) == 0) {}
      fast = (g == 1);
    }
    sh_slot = work ? slot : -1;
    sh_fast = fast;
  }
  __syncthreads();
  const int slot = sh_slot;
  if (slot < 0) return;
  const bool fastmode = (sh_fast != 0);

  const ScanDesc d = args.d[slot / NB];
  const int b = slot % NB;
  const int slice = tid % TPU, ug = tid / TPU;
  const int unit = b * UPB + ug;
  const int wid = tid >> 6, lane = tid & 63;

  float wr[KS], wz[KS], wn[KS];
#pragma unroll
  for (int j2 = 0; j2 < KS / 4; ++j2)
#pragma unroll
    for (int r = 0; r < 4; ++r) {
      int k = slice * 4 + 4 * TPU * j2 + r;
      int j = 4 * j2 + r;
      wr[j] = d.whhT[(size_t)(0 * H + unit) * H + k];
      wz[j] = d.whhT[(size_t)(1 * H + unit) * H + k];
      wn[j] = d.whhT[(size_t)(2 * H + unit) * H + k];
    }
  const float bhr = d.bhh[unit];
  const float bhz = d.bhh[H + unit];
  const float bhn = d.bhh[2 * H + unit];

  __shared__ float hsh[2][H];
  __shared__ int flag;
  for (int i = tid; i < H; i += B) hsh[0][i] = 0.f;
  if (tid == 0) flag = 0;
  __syncthreads();

  const int T = d.T, dir = d.dir, stride = d.stride, off = d.off;
  uint32_t* __restrict__ hwS = d.hwS;
  uint32_t* __restrict__ hwF = d.hwF;

  for (int s = 0; s < T; ++s) {
    const int pos = dir ? (T - 1 - s) : s;
    const int cur = s & 1;
    const float* prow = d.pre + (size_t)pos * (3 * H);
    const float pir = prow[unit];
    const float piz = prow[H + unit];
    const float pin = prow[2 * H + unit];

    if (s > 0) {
      if (wid == 0) {
        const uint32_t want = (uint32_t)s;  // h(s-1) words carry seq = s
        const uint32_t* fsrc = hwF + (size_t)(s - 1) * H + lane;
        const uint32_t* ssrc = hwS + (size_t)(s - 1) * H + lane;
        uint32_t w[PP];
        if (fastmode) {
          int rounds = 0;
          for (;;) {
            fast_poll32<PP>(fsrc, w);
            bool ok = true;
#pragma unroll
            for (int p = 0; p < PP; ++p) ok = ok && ((w[p] >> 16) == want);
            if (__all(ok)) break;
            if ((++rounds & 15) == 0) {  // liveness fallback
              bool ok2 = true;
#pragma unroll
              for (int p = 0; p < PP; ++p)
                w[p] = __hip_atomic_load(ssrc + 64 * p, __ATOMIC_RELAXED,
                                         __HIP_MEMORY_SCOPE_AGENT);
#pragma unroll
              for (int p = 0; p < PP; ++p)
                ok2 = ok2 && ((w[p] >> 16) == want);
              if (__all(ok2)) break;
            }
          }
        } else {
          for (;;) {
            bool ok = true;
#pragma unroll
            for (int p = 0; p < PP; ++p)
              w[p] = __hip_atomic_load(ssrc + 64 * p, __ATOMIC_RELAXED,
                                       __HIP_MEMORY_SCOPE_AGENT);
#pragma unroll
            for (int p = 0; p < PP; ++p) ok = ok && ((w[p] >> 16) == want);
            if (__all(ok)) break;
          }
        }
#pragma unroll
        for (int p = 0; p < PP; ++p)
          hsh[cur][lane + 64 * p] = b2f((ushort)(w[p] & 0xffffu));
        __hip_atomic_store(&flag, s, __ATOMIC_RELEASE,
                           __HIP_MEMORY_SCOPE_WORKGROUP);
      } else {
        while (__hip_atomic_load(&flag, __ATOMIC_ACQUIRE,
                                 __HIP_MEMORY_SCOPE_WORKGROUP) < s) {}
      }
    }

    float ar = 0.f, az = 0.f, an = 0.f;
    const float* hrow = hsh[cur];
#pragma unroll
    for (int j2 = 0; j2 < KS / 4; ++j2) {
      const float4 hv = *(const float4*)&hrow[slice * 4 + 4 * TPU * j2];
      const int j = 4 * j2;
      ar = fmaf(wr[j], hv.x, ar); ar = fmaf(wr[j + 1], hv.y, ar);
      ar = fmaf(wr[j + 2], hv.z, ar); ar = fmaf(wr[j + 3], hv.w, ar);
      az = fmaf(wz[j], hv.x, az); az = fmaf(wz[j + 1], hv.y, az);
      az = fmaf(wz[j + 2], hv.z, az); az = fmaf(wz[j + 3], hv.w, az);
      an = fmaf(wn[j], hv.x, an); an = fmaf(wn[j + 1], hv.y, an);
      an = fmaf(wn[j + 2], hv.z, an); an = fmaf(wn[j + 3], hv.w, an);
    }
    ar = dpp_reduce<TPU>(ar);
    az = dpp_reduce<TPU>(az);
    an = dpp_reduce<TPU>(an);

    if (slice == 0) {
      const float hp = hrow[unit];
      float r = fsig(pir + ar + bhr);
      float z = fsig(piz + az + bhz);
      float n = ftanh(pin + r * (an + bhn));
      float hn = (1.f - z) * n + z * hp;
      const ushort hb = f2bu(hn);
      d.out[(size_t)pos * stride + off + unit] = hn;
      if (d.outb) d.outb[(size_t)pos * d.bstride + d.boff + unit] = hb;
      if (d.outbT) d.outbT[(size_t)unit * d.tld + pos] = hb;
      uint32_t wv = ((uint32_t)(s + 1) << 16) | (uint32_t)hb;
      if (fastmode) store_sc0_u32(&hwF[(size_t)s * H + unit], wv);
      __hip_atomic_store(&hwS[(size_t)s * H + unit], wv, __ATOMIC_RELAXED,
                         __HIP_MEMORY_SCOPE_AGENT);
    }
    // double-buffered hsh + external data dependency act as the barrier.
  }
}

// ---------------------------------------------------------------------------
// Cross-modal attention (bf16 q/k in, bf16 Xcm out)
// ---------------------------------------------------------------------------
__global__ __launch_bounds__(256)
void cma_kernel(const ushort* __restrict__ qv, const ushort* __restrict__ ksm,
                const float* __restrict__ cmav, const float* __restrict__ Hv,
                const float* __restrict__ Hs, ushort* __restrict__ Xcm) {
  const int t = blockIdx.x, tid = threadIdx.x;
  const int lane = tid & 63, wave = tid >> 6;
  __shared__ float qsh[512], vsh[512], wsm[32];
  qsh[tid] = b2f(qv[t * 512 + tid]);
  qsh[256 + tid] = b2f(qv[t * 512 + 256 + tid]);
  vsh[tid] = cmav[tid];
  vsh[256 + tid] = cmav[256 + tid];
  __syncthreads();
  for (int s = wave; s < 32; s += 4) {
    float p = 0.f;
#pragma unroll
    for (int j = 0; j < 8; ++j) {
      int c = lane + 64 * j;
      p += ftanh(qsh[c] + b2f(ksm[s * 512 + c])) * vsh[c];
    }
#pragma unroll
    for (int m = 32; m >= 1; m >>= 1) p += __shfl_xor(p, m, 64);
    if (lane == 0) wsm[s] = p;
  }
  __syncthreads();
  float mx = -1e30f;
  for (int s = 0; s < 32; ++s) mx = fmaxf(mx, wsm[s]);
  float sum = 0.f;
  for (int s = 0; s < 32; ++s) sum += __expf(wsm[s] - mx);
  float inv = 1.f / sum;
  __syncthreads();
  if (tid < 32) wsm[tid] = __expf(wsm[tid] - mx) * inv;
  __syncthreads();
#pragma unroll
  for (int rep = 0; rep < 2; ++rep) {
    int c = tid + 256 * rep;
    float acc = 0.f;
#pragma unroll
    for (int s = 0; s < 32; ++s) acc += wsm[s] * Hs[s * 512 + c];
    float hb = acc;
    float hv = fmaxf(Hv[(size_t)t * 512 + c], 0.f) * hb;
    float hs2 = fmaxf(hb, 0.f) * hv;
    Xcm[(size_t)t * 1024 + c] = f2bu(hv);
    Xcm[(size_t)t * 1024 + 512 + c] = f2bu(hs2);
  }
}

// ---------------------------------------------------------------------------
// Masked self-attention scores: P[i][j] = softmax_j>=i(tanh dot), bf16,
// zeros for j<i. Also copies Xsi[i][0:512] = hr_b[i].
// ---------------------------------------------------------------------------
__global__ __launch_bounds__(256)
void selfatt_score(const ushort* __restrict__ q2, const ushort* __restrict__ k2,
                   const float* __restrict__ siv, const ushort* __restrict__ hrb,
                   ushort* __restrict__ P, ushort* __restrict__ Xsi) {
  const int i = blockIdx.x, tid = threadIdx.x;
  const int lane = tid & 63, wave = tid >> 6;
  __shared__ float qsh[512], vsh[512], scr[512];
  qsh[tid] = b2f(q2[(size_t)i * 512 + tid]);
  qsh[256 + tid] = b2f(q2[(size_t)i * 512 + 256 + tid]);
  vsh[tid] = siv[tid];
  vsh[256 + tid] = siv[256 + tid];
  Xsi[(size_t)i * 1024 + tid] = hrb[(size_t)i * 512 + tid];
  Xsi[(size_t)i * 1024 + 256 + tid] = hrb[(size_t)i * 512 + 256 + tid];
  __syncthreads();
  for (int j = i + wave; j < 512; j += 4) {
    float p = 0.f;
#pragma unroll
    for (int r = 0; r < 8; ++r) {
      int c = lane + 64 * r;
      p += ftanh(qsh[c] + b2f(k2[(size_t)j * 512 + c])) * vsh[c];
    }
#pragma unroll
    for (int m = 32; m >= 1; m >>= 1) p += __shfl_xor(p, m, 64);
    if (lane == 0) scr[j] = p;
  }
  __syncthreads();
  float mx = -1e30f;
  for (int j = i; j < 512; ++j) mx = fmaxf(mx, scr[j]);
  float sum = 0.f;
  for (int j = i; j < 512; ++j) sum += __expf(scr[j] - mx);
  float inv = 1.f / sum;
  __syncthreads();
  for (int j = tid; j < 512; j += 256) {
    float p = (j >= i) ? __expf(scr[j] - mx) * inv : 0.f;
    P[(size_t)i * 512 + j] = f2bu(p);
  }
}

// ---------------------------------------------------------------------------
__global__ void ho_kernel(const float* __restrict__ Hs, float* __restrict__ ho) {
  int c = blockIdx.x * 256 + threadIdx.x;
  float a = 0.f;
#pragma unroll
  for (int s = 0; s < 32; ++s) a += Hs[s * 512 + c];
  ho[c] = a;
}

__global__ void cat_kernel(const float* __restrict__ hd,
                           const float* __restrict__ ho,
                           ushort* __restrict__ cat) {
  int i = blockIdx.x, tid = threadIdx.x;
#pragma unroll
  for (int r = 0; r < 4; ++r) {
    int k = tid + 256 * r;
    float v = (k < 512) ? hd[(size_t)i * 512 + k] : ho[k - 512];
    cat[(size_t)i * 1024 + k] = f2bu(v);
  }
}

__global__ __launch_bounds__(256)
void score_kernel(const float* __restrict__ tmp, const float* __restrict__ cpv,
                  float* __restrict__ out) {
  const int i = blockIdx.x, tid = threadIdx.x;
  float p = tmp[(size_t)i * 512 + tid] * cpv[tid] +
            tmp[(size_t)i * 512 + 256 + tid] * cpv[256 + tid];
#pragma unroll
  for (int m = 32; m >= 1; m >>= 1) p += __shfl_xor(p, m, 64);
  __shared__ float wsum[4];
  if ((tid & 63) == 0) wsum[tid >> 6] = p;
  __syncthreads();
  if (tid == 0) {
    out[i] = wsum[0] + wsum[1] + wsum[2] + wsum[3];
    out[497 + i] = (float)i;  // window_starts as float32
  }
}

// ---------------------------------------------------------------------------
extern "C" void kernel_launch(void* const* d_in, const int* in_sizes, int n_in,
                              void* d_out, int out_size, void* d_ws,
                              size_t ws_size, hipStream_t stream) {
  const float* video = (const float*)d_in[0];
  const int* text = (const int*)d_in[1];
  const float* vp_W = (const float*)d_in[2];
  const float* vp_b = (const float*)d_in[3];
  const float* vWih = (const float*)d_in[4];
  const float* vWhh = (const float*)d_in[5];
  const float* vbih = (const float*)d_in[6];
  const float* vbhh = (const float*)d_in[7];
  const float* emb = (const float*)d_in[8];
  const float* tp_W = (const float*)d_in[9];
  const float* tp_b = (const float*)d_in[10];
  const float* tWih = (const float*)d_in[11];
  const float* tWhh = (const float*)d_in[12];
  const float* tbih = (const float*)d_in[13];
  const float* tbhh = (const float*)d_in[14];
  const float* cmaWq = (const float*)d_in[15];
  const float* cmabq = (const float*)d_in[16];
  const float* cmaWk = (const float*)d_in[17];
  const float* cmabk = (const float*)d_in[18];
  const float* cmav = (const float*)d_in[19];
  const float* cmWih = (const float*)d_in[20];
  const float* cmWhh = (const float*)d_in[21];
  const float* cmbih = (const float*)d_in[22];
  const float* cmbhh = (const float*)d_in[23];
  const float* siWq = (const float*)d_in[24];
  const float* sibq = (const float*)d_in[25];
  const float* siWk = (const float*)d_in[26];
  const float* sibk = (const float*)d_in[27];
  const float* siv = (const float*)d_in[28];
  const float* sgWih = (const float*)d_in[29];
  const float* sgWhh = (const float*)d_in[30];
  const float* sgbih = (const float*)d_in[31];
  const float* sgbhh = (const float*)d_in[32];
  // d_in[33..35] dead (softmax over singleton axis == 1)
  const float* cpW1 = (const float*)d_in[36];
  const float* cpb1 = (const float*)d_in[37];
  const float* cpv = (const float*)d_in[38];
  float* out = (float*)d_out;

  float* ws = (float*)d_ws;
  size_t off = 0;
  auto alloc = [&](size_t n) {  // n in floats
    float* p = ws + off;
    off += (n + 3) & ~(size_t)3;
    return p;
  };
  auto allocU = [&](size_t n) { return (ushort*)alloc((n + 1) / 2); };
  // activations
  ushort* video_b = allocU(512 * 1024);
  ushort* x_emb_b = allocU(32 * 320);
  ushort* x_v_b = allocU(512 * 512);
  ushort* x_s_b = allocU(32 * 512);
  float* pre_v = alloc(2 * 512 * 768);
  float* pre_s = alloc(2 * 32 * 768);
  float* Hv = alloc(512 * 512);
  ushort* Hv_b = allocU(512 * 512);
  float* Hs = alloc(32 * 512);
  ushort* Hs_b = allocU(32 * 512);
  ushort* qv_b = allocU(512 * 512);
  ushort* ksb_b = allocU(32 * 512);
  ushort* Xcm_b = allocU(512 * 1024);
  float* pre_cm = alloc(512 * 1536);
  float* hr = alloc(512 * 512);
  ushort* hr_b = allocU(512 * 512);
  ushort* hrT_b = allocU(512 * 512);
  ushort* q2_b = allocU(512 * 512);
  ushort* k2_b = allocU(512 * 512);
  ushort* P_b = allocU(512 * 512);
  ushort* Xsi_b = allocU(512 * 1024);
  float* pre_si = alloc(512 * 1536);
  float* hd = alloc(512 * 512);
  float* ho = alloc(512);
  ushort* cat_b = allocU(512 * 1024);
  float* tmpb = alloc(512 * 512);
  // scan weights (fp32 transposed)
  float* whhT_v = alloc(2 * 768 * 256);
  float* whhT_t = alloc(2 * 768 * 256);
  float* whhT_cm = alloc(1536 * 512);
  float* whhT_si = alloc(1536 * 512);
  // GEMM weights (bf16 transposed [N][Kp])
  ushort* vpW_T = allocU(512 * 1024);
  ushort* vWihT_f = allocU(768 * 512);
  ushort* vWihT_b = allocU(768 * 512);
  ushort* tpW_T = allocU(512 * 320);
  ushort* tWihT_f = allocU(768 * 512);
  ushort* tWihT_b = allocU(768 * 512);
  ushort* cmaWqT = allocU(512 * 512);
  ushort* cmaWkT = allocU(512 * 512);
  ushort* cmWihT = allocU(1536 * 1024);
  ushort* siWqT = allocU(512 * 512);
  ushort* siWkT = allocU(512 * 512);
  ushort* sgWihT = allocU(1536 * 1024);
  ushort* cpW1T = allocU(512 * 1024);
  // handoff words (slow + fast) + per-launch ctrl, contiguous, zeroed
  float* zero0 = ws + off;
  uint32_t* hwS_vf = (uint32_t*)alloc(512 * 256);
  uint32_t* hwS_vb = (uint32_t*)alloc(512 * 256);
  uint32_t* hwS_tf = (uint32_t*)alloc(32 * 256);
  uint32_t* hwS_tb = (uint32_t*)alloc(32 * 256);
  uint32_t* hwS_cm = (uint32_t*)alloc(512 * 512);
  uint32_t* hwS_si = (uint32_t*)alloc(512 * 512);
  uint32_t* hwF_vf = (uint32_t*)alloc(512 * 256);
  uint32_t* hwF_vb = (uint32_t*)alloc(512 * 256);
  uint32_t* hwF_tf = (uint32_t*)alloc(32 * 256);
  uint32_t* hwF_tb = (uint32_t*)alloc(32 * 256);
  uint32_t* hwF_cm = (uint32_t*)alloc(512 * 512);
  uint32_t* hwF_si = (uint32_t*)alloc(512 * 512);
  uint32_t* ctrl1 = (uint32_t*)alloc(256);
  uint32_t* ctrl2 = (uint32_t*)alloc(256);
  uint32_t* ctrl3 = (uint32_t*)alloc(256);
  size_t zero_bytes = ((ws + off) - zero0) * sizeof(float);
  hipMemsetAsync(zero0, 0, zero_bytes, stream);

  // ---- weight prep (one batched launch) ----
  PrepArgs pa{};
  int nd = 0;
  size_t total_tiles = 0;
  auto addT = [&](const float* src, ushort* db, float* df, int K, int N, int Kp) {
    pa.d[nd++] = TDesc{src, db, df, K, N, Kp};
    total_tiles += (size_t)((N + 31) / 32) * ((Kp + 31) / 32);
  };
  addT(vWhh, nullptr, whhT_v, 256, 768, 256);
  addT(vWhh + 196608, nullptr, whhT_v + 196608, 256, 768, 256);
  addT(tWhh, nullptr, whhT_t, 256, 768, 256);
  addT(tWhh + 196608, nullptr, whhT_t + 196608, 256, 768, 256);
  addT(cmWhh, nullptr, whhT_cm, 512, 1536, 512);
  addT(sgWhh, nullptr, whhT_si, 512, 1536, 512);
  addT(vp_W, vpW_T, nullptr, 1024, 512, 1024);
  addT(vWih, vWihT_f, nullptr, 512, 768, 512);
  addT(vWih + 393216, vWihT_b, nullptr, 512, 768, 512);
  addT(tp_W, tpW_T, nullptr, 300, 512, 320);
  addT(tWih, tWihT_f, nullptr, 512, 768, 512);
  addT(tWih + 393216, tWihT_b, nullptr, 512, 768, 512);
  addT(cmaWq, cmaWqT, nullptr, 512, 512, 512);
  addT(cmaWk, cmaWkT, nullptr, 512, 512, 512);
  addT(cmWih, cmWihT, nullptr, 1024, 1536, 1024);
  addT(siWq, siWqT, nullptr, 512, 512, 512);
  addT(siWk, siWkT, nullptr, 512, 512, 512);
  addT(sgWih, sgWihT, nullptr, 1024, 1536, 1024);
  addT(cpW1, cpW1T, nullptr, 1024, 512, 1024);
  pa.n = nd;
  prep_kernel<<<(int)total_tiles, 256, 0, stream>>>(pa);

  cast_kernel<<<512, 256, 0, stream>>>(video, video_b, 512 * 1024);
  emb_kernel<<<32, 256, 0, stream>>>(emb, text, x_emb_b);

  // projections + GRU input pre-activations (MFMA)
  mfma_gemm<<<dim3(8, 8), 256, 0, stream>>>(video_b, vpW_T, vp_b, x_v_b, 512, 512, 1024, 512, 2);
  mfma_gemm<<<dim3(12, 8), 256, 0, stream>>>(x_v_b, vWihT_f, vbih, pre_v, 512, 768, 512, 768, 0);
  mfma_gemm<<<dim3(12, 8), 256, 0, stream>>>(x_v_b, vWihT_b, vbih + 768, pre_v + 393216, 512, 768, 512, 768, 0);
  mfma_gemm<<<dim3(8, 1), 256, 0, stream>>>(x_emb_b, tpW_T, tp_b, x_s_b, 32, 512, 320, 512, 2);
  mfma_gemm<<<dim3(12, 1), 256, 0, stream>>>(x_s_b, tWihT_f, tbih, pre_s, 32, 768, 512, 768, 0);
  mfma_gemm<<<dim3(12, 1), 256, 0, stream>>>(x_s_b, tWihT_b, tbih + 768, pre_s + 24576, 32, 768, 512, 768, 0);

  // video + text BiGRU scans (4 instances x NB=8 workers on one XCD)
  ScanArgs a1{};
  a1.d[0] = ScanDesc{whhT_v, vbhh, pre_v, Hv, Hv_b, nullptr, hwS_vf, hwF_vf, 512, 0, 512, 0, 512, 0, 0};
  a1.d[1] = ScanDesc{whhT_v + 196608, vbhh + 768, pre_v + 393216, Hv, Hv_b, nullptr, hwS_vb, hwF_vb, 512, 1, 512, 256, 512, 256, 0};
  a1.d[2] = ScanDesc{whhT_t, tbhh, pre_s, Hs, Hs_b, nullptr, hwS_tf, hwF_tf, 32, 0, 512, 0, 512, 0, 0};
  a1.d[3] = ScanDesc{whhT_t + 196608, tbhh + 768, pre_s + 24576, Hs, Hs_b, nullptr, hwS_tb, hwF_tb, 32, 1, 512, 256, 512, 256, 0};
  a1.ctrl = ctrl1;
  scan_kernel<256, 8, 8, 4><<<256, 256, 0, stream>>>(a1);

  // cross-modal attention
  mfma_gemm<<<dim3(8, 8), 256, 0, stream>>>(Hv_b, cmaWqT, cmabq, qv_b, 512, 512, 512, 512, 2);
  mfma_gemm<<<dim3(8, 1), 256, 0, stream>>>(Hs_b, cmaWkT, cmabk, ksb_b, 32, 512, 512, 512, 2);
  cma_kernel<<<512, 256, 0, stream>>>(qv_b, ksb_b, cmav, Hv, Hs, Xcm_b);
  mfma_gemm<<<dim3(24, 8), 256, 0, stream>>>(Xcm_b, cmWihT, cmbih, pre_cm, 512, 1536, 1024, 1536, 0);

  ScanArgs a2{};
  a2.d[0] = ScanDesc{whhT_cm, cmbhh, pre_cm, hr, hr_b, hrT_b, hwS_cm, hwF_cm, 512, 0, 512, 0, 512, 0, 512};
  a2.ctrl = ctrl2;
  scan_kernel<512, 32, 16, 1><<<256, 256, 0, stream>>>(a2);

  // masked self-attention: scores+softmax (vector) then PV via MFMA
  mfma_gemm<<<dim3(8, 8), 256, 0, stream>>>(hr_b, siWqT, sibq, q2_b, 512, 512, 512, 512, 2);
  mfma_gemm<<<dim3(8, 8), 256, 0, stream>>>(hr_b, siWkT, sibk, k2_b, 512, 512, 512, 512, 2);
  selfatt_score<<<512, 256, 0, stream>>>(q2_b, k2_b, siv, hr_b, P_b, Xsi_b);
  mfma_gemm<<<dim3(8, 8), 256, 0, stream>>>(P_b, hrT_b, nullptr, Xsi_b + 512, 512, 512, 512, 1024, 2);
  mfma_gemm<<<dim3(24, 8), 256, 0, stream>>>(Xsi_b, sgWihT, sgbih, pre_si, 512, 1536, 1024, 1536, 0);

  ScanArgs a3{};
  a3.d[0] = ScanDesc{whhT_si, sgbhh, pre_si, hd, nullptr, nullptr, hwS_si, hwF_si, 512, 0, 512, 0, 0, 0, 0};
  a3.ctrl = ctrl3;
  scan_kernel<512, 32, 16, 1><<<256, 256, 0, stream>>>(a3);

  // scoring head
  ho_kernel<<<2, 256, 0, stream>>>(Hs, ho);
  cat_kernel<<<512, 256, 0, stream>>>(hd, ho, cat_b);
  mfma_gemm<<<dim3(8, 8), 256, 0, stream>>>(cat_b, cpW1T, cpb1, tmpb, 512, 512, 1024, 512, 1);
  score_kernel<<<497, 256, 0, stream>>>(tmpb, cpv, out);
}

// Round 7
// 4075.665 us; speedup vs baseline: 1.4356x; 1.4356x over previous
//
#include <hip/hip_runtime.h>
#include <hip/hip_bf16.h>
#include <cstdint>

#define DEV __device__ __forceinline__

typedef unsigned short ushort;
typedef __attribute__((ext_vector_type(8))) short bf16x8;
typedef __attribute__((ext_vector_type(4))) float f32x4;

DEV float fsig(float x) { return 1.f / (1.f + __expf(-x)); }
DEV float ftanh(float x) { return 1.f - 2.f / (1.f + __expf(2.f * x)); }
DEV ushort f2bu(float f) {
  __hip_bfloat16 h = __float2bfloat16(f);
  return *(ushort*)&h;
}
DEV float b2f(ushort u) { return __uint_as_float((uint32_t)u << 16); }

// DPP butterfly add within TPU-sized groups (no DS pipe).
template <int CTRL>
DEV float dpp_add(float v) {
  int x = __builtin_amdgcn_update_dpp(0, __float_as_int(v), CTRL, 0xF, 0xF, true);
  return v + __int_as_float(x);
}
template <int TPU>
DEV float dpp_reduce(float v) {
  v = dpp_add<0xB1>(v);
  v = dpp_add<0x4E>(v);
  if (TPU >= 8) v = dpp_add<0x141>(v);
  if (TPU >= 16) v = dpp_add<0x140>(v);
  return v;
}

// ---------------------------------------------------------------------------
// MFMA bf16 GEMM: C[M,N](ldc) = act(A[M,K]_bf16 @ (BT[N,K]_bf16)^T + bias)
// flags: 1 = tanh, 2 = bf16 output. N%64==0, K%32==0; M guarded. bias nullable.
// ---------------------------------------------------------------------------
__global__ __launch_bounds__(256)
void mfma_gemm(const ushort* __restrict__ A, const ushort* __restrict__ BT,
               const float* __restrict__ bias, void* __restrict__ Cout,
               int M, int N, int K, int ldc, int flags) {
  const int wave = threadIdx.x >> 6, lane = threadIdx.x & 63;
  const int m0 = blockIdx.y * 64 + wave * 16;
  const int n0 = blockIdx.x * 64;
  const int r = lane & 15, quad = lane >> 4;
  f32x4 acc[4] = {};
  const int arow = (m0 + r < M) ? (m0 + r) : 0;
  const ushort* ap = A + (size_t)arow * K + quad * 8;
  const ushort* bp = BT + (size_t)(n0 + r) * K + quad * 8;
#pragma unroll 2
  for (int k0 = 0; k0 < K; k0 += 32) {
    bf16x8 a = *(const bf16x8*)(ap + k0);
#pragma unroll
    for (int t = 0; t < 4; ++t) {
      bf16x8 b = *(const bf16x8*)(bp + (size_t)t * 16 * K + k0);
      acc[t] = __builtin_amdgcn_mfma_f32_16x16x32_bf16(a, b, acc[t], 0, 0, 0);
    }
  }
#pragma unroll
  for (int t = 0; t < 4; ++t) {
    const int col = n0 + t * 16 + r;
    const float bs = bias ? bias[col] : 0.f;
#pragma unroll
    for (int e = 0; e < 4; ++e) {
      const int row = m0 + quad * 4 + e;
      if (row < M) {
        float v = acc[t][e] + bs;
        if (flags & 1) v = ftanh(v);
        if (flags & 2)
          ((ushort*)Cout)[(size_t)row * ldc + col] = f2bu(v);
        else
          ((float*)Cout)[(size_t)row * ldc + col] = v;
      }
    }
  }
}

// ---------------------------------------------------------------------------
// Batched transpose(+pad) prep: src fp32 [K][N] -> dst [N][Kp] (bf16 or fp32)
// ---------------------------------------------------------------------------
struct TDesc {
  const float* src;
  ushort* db;
  float* df;
  int K, N, Kp;
};
struct PrepArgs {
  TDesc d[19];
  int n;
};

__global__ __launch_bounds__(256)
void prep_kernel(PrepArgs pa) {
  int rem = blockIdx.x;
  int di = 0;
  TDesc d{};
  for (; di < pa.n; ++di) {
    d = pa.d[di];
    int t = ((d.N + 31) >> 5) * ((d.Kp + 31) >> 5);
    if (rem < t) break;
    rem -= t;
  }
  if (di == pa.n) return;
  const int ntx = (d.Kp + 31) >> 5;
  const int ty = rem / ntx, tx = rem % ntx;
  __shared__ float t32[32][33];
  const int lx = threadIdx.x & 31, ly = threadIdx.x >> 5;
#pragma unroll
  for (int p = 0; p < 4; ++p) {
    int k = tx * 32 + ly + 8 * p;
    int n = ty * 32 + lx;
    t32[ly + 8 * p][lx] = (k < d.K && n < d.N) ? d.src[(size_t)k * d.N + n] : 0.f;
  }
  __syncthreads();
#pragma unroll
  for (int p = 0; p < 4; ++p) {
    int n = ty * 32 + ly + 8 * p;
    int k = tx * 32 + lx;
    if (n < d.N && k < d.Kp) {
      float v = t32[lx][ly + 8 * p];
      if (d.df)
        d.df[(size_t)n * d.Kp + k] = v;
      else
        d.db[(size_t)n * d.Kp + k] = f2bu(v);
    }
  }
}

__global__ void cast_kernel(const float* __restrict__ in,
                            ushort* __restrict__ out, int n) {
  int i = (blockIdx.x * 256 + threadIdx.x) * 4;
  if (i + 3 < n) {
    float4 v = *(const float4*)(in + i);
    out[i] = f2bu(v.x);
    out[i + 1] = f2bu(v.y);
    out[i + 2] = f2bu(v.z);
    out[i + 3] = f2bu(v.w);
  }
}

__global__ void emb_kernel(const float* __restrict__ emb,
                           const int* __restrict__ text,
                           ushort* __restrict__ xe) {
  int s = blockIdx.x;
  int row = text[s];
  for (int k = threadIdx.x; k < 320; k += 256)
    xe[s * 320 + k] = (k < 300) ? f2bu(emb[(size_t)row * 300 + k]) : (ushort)0;
}

// ---------------------------------------------------------------------------
// Persistent multi-block GRU scan, v7 (= R3 protocol + micro-opts).
// Handoff: (seq16<<16)|bf16(h) words, relaxed agent-scope (LLC) stores/loads;
// poison 0xAAAA / memset-0 never equal a valid seq in [1,T].
// Wave 0 polls (batched), stages LDS, releases LDS flag; other waves spin
// with s_sleep (no DS-pipe contention). Producer issues the handoff store
// BEFORE any mirror stores. Dead fp32 mirrors removed by callers.
// ---------------------------------------------------------------------------
struct ScanDesc {
  const float* whhT;  // [3H][H]
  const float* bhh;   // [3H]
  const float* pre;   // [T][3H]
  float* out;         // optional fp32 out[pos*stride + off + unit]
  ushort* outb;       // optional bf16 mirror [pos*bstride + boff + unit]
  ushort* outbT;      // optional bf16 transposed mirror [unit*tld + pos]
  uint32_t* hw;       // [T][H] handoff words, zeroed per launch
  int T, dir, stride, off, bstride, boff, tld;
};
struct ScanArgs {
  ScanDesc d[4];
};

template <int H, int NB, int TPU>
__global__ __launch_bounds__(256, 1)
void scan_kernel(ScanArgs args) {
  constexpr int UPB = H / NB;   // units per block
  constexpr int B = UPB * TPU;  // block threads (256)
  constexpr int KS = H / TPU;   // k elems per thread (32)
  constexpr int PP = H / 64;    // words per wave0-lane per poll
  const ScanDesc d = args.d[blockIdx.x / NB];
  const int b = blockIdx.x % NB;
  const int tid = threadIdx.x;
  const int slice = tid % TPU, ug = tid / TPU;
  const int unit = b * UPB + ug;
  const int wid = tid >> 6, lane = tid & 63;

  float wr[KS], wz[KS], wn[KS];
#pragma unroll
  for (int j2 = 0; j2 < KS / 4; ++j2)
#pragma unroll
    for (int r = 0; r < 4; ++r) {
      int k = slice * 4 + 4 * TPU * j2 + r;
      int j = 4 * j2 + r;
      wr[j] = d.whhT[(size_t)(0 * H + unit) * H + k];
      wz[j] = d.whhT[(size_t)(1 * H + unit) * H + k];
      wn[j] = d.whhT[(size_t)(2 * H + unit) * H + k];
    }
  const float bhr = d.bhh[unit];
  const float bhz = d.bhh[H + unit];
  const float bhn = d.bhh[2 * H + unit];

  __shared__ float hsh[2][H];
  __shared__ int flag;
  for (int i = tid; i < H; i += B) hsh[0][i] = 0.f;
  if (tid == 0) flag = 0;  // step 0 pre-staged (h = 0)
  __syncthreads();

  const int T = d.T, dir = d.dir, stride = d.stride, off = d.off;
  uint32_t* __restrict__ hw = d.hw;

  for (int s = 0; s < T; ++s) {
    const int pos = dir ? (T - 1 - s) : s;
    const int cur = s & 1;
    // prefetch pre-row (h-independent) — overlaps the handoff wait
    const float* prow = d.pre + (size_t)pos * (3 * H);
    const float pir = prow[unit];
    const float piz = prow[H + unit];
    const float pin = prow[2 * H + unit];

    if (s > 0) {
      if (wid == 0) {
        const uint32_t want = (uint32_t)s;  // h(s-1) words carry seq = s
        const uint32_t* src = hw + (size_t)(s - 1) * H + lane;
        uint32_t w[PP];
        for (;;) {
          bool ok = true;
#pragma unroll
          for (int p = 0; p < PP; ++p)
            w[p] = __hip_atomic_load(src + 64 * p, __ATOMIC_RELAXED,
                                     __HIP_MEMORY_SCOPE_AGENT);
#pragma unroll
          for (int p = 0; p < PP; ++p) ok = ok && ((w[p] >> 16) == want);
          if (__all(ok)) break;
        }
#pragma unroll
        for (int p = 0; p < PP; ++p)
          hsh[cur][lane + 64 * p] = b2f((ushort)(w[p] & 0xffffu));
        __hip_atomic_store(&flag, s, __ATOMIC_RELEASE,
                           __HIP_MEMORY_SCOPE_WORKGROUP);
      } else {
        while (__hip_atomic_load(&flag, __ATOMIC_ACQUIRE,
                                 __HIP_MEMORY_SCOPE_WORKGROUP) < s)
          __builtin_amdgcn_s_sleep(1);
      }
    }

    float ar = 0.f, az = 0.f, an = 0.f;
    const float* hrow = hsh[cur];
#pragma unroll
    for (int j2 = 0; j2 < KS / 4; ++j2) {
      const float4 hv = *(const float4*)&hrow[slice * 4 + 4 * TPU * j2];
      const int j = 4 * j2;
      ar = fmaf(wr[j], hv.x, ar); ar = fmaf(wr[j + 1], hv.y, ar);
      ar = fmaf(wr[j + 2], hv.z, ar); ar = fmaf(wr[j + 3], hv.w, ar);
      az = fmaf(wz[j], hv.x, az); az = fmaf(wz[j + 1], hv.y, az);
      az = fmaf(wz[j + 2], hv.z, az); az = fmaf(wz[j + 3], hv.w, az);
      an = fmaf(wn[j], hv.x, an); an = fmaf(wn[j + 1], hv.y, an);
      an = fmaf(wn[j + 2], hv.z, an); an = fmaf(wn[j + 3], hv.w, an);
    }
    ar = dpp_reduce<TPU>(ar);
    az = dpp_reduce<TPU>(az);
    an = dpp_reduce<TPU>(an);

    if (slice == 0) {
      const float hp = hrow[unit];
      float r = fsig(pir + ar + bhr);
      float z = fsig(piz + az + bhz);
      float n = ftanh(pin + r * (an + bhn));
      float hn = (1.f - z) * n + z * hp;
      const ushort hb = f2bu(hn);
      // handoff store FIRST — it is the critical path
      uint32_t wv = ((uint32_t)(s + 1) << 16) | (uint32_t)hb;
      __hip_atomic_store(&hw[(size_t)s * H + unit], wv, __ATOMIC_RELAXED,
                         __HIP_MEMORY_SCOPE_AGENT);
      if (d.out) d.out[(size_t)pos * stride + off + unit] = hn;
      if (d.outb) d.outb[(size_t)pos * d.bstride + d.boff + unit] = hb;
      if (d.outbT) d.outbT[(size_t)unit * d.tld + pos] = hb;
    }
    // double-buffered hsh + seq-tagged handoff: no per-step barrier needed
  }
}

// ---------------------------------------------------------------------------
// Cross-modal attention (bf16 q/k in, bf16 Xcm out)
// ---------------------------------------------------------------------------
__global__ __launch_bounds__(256)
void cma_kernel(const ushort* __restrict__ qv, const ushort* __restrict__ ksm,
                const float* __restrict__ cmav, const float* __restrict__ Hv,
                const float* __restrict__ Hs, ushort* __restrict__ Xcm) {
  const int t = blockIdx.x, tid = threadIdx.x;
  const int lane = tid & 63, wave = tid >> 6;
  __shared__ float qsh[512], vsh[512], wsm[32];
  qsh[tid] = b2f(qv[t * 512 + tid]);
  qsh[256 + tid] = b2f(qv[t * 512 + 256 + tid]);
  vsh[tid] = cmav[tid];
  vsh[256 + tid] = cmav[256 + tid];
  __syncthreads();
  for (int s = wave; s < 32; s += 4) {
    float p = 0.f;
#pragma unroll
    for (int j = 0; j < 8; ++j) {
      int c = lane + 64 * j;
      p += ftanh(qsh[c] + b2f(ksm[s * 512 + c])) * vsh[c];
    }
#pragma unroll
    for (int m = 32; m >= 1; m >>= 1) p += __shfl_xor(p, m, 64);
    if (lane == 0) wsm[s] = p;
  }
  __syncthreads();
  float mx = -1e30f;
  for (int s = 0; s < 32; ++s) mx = fmaxf(mx, wsm[s]);
  float sum = 0.f;
  for (int s = 0; s < 32; ++s) sum += __expf(wsm[s] - mx);
  float inv = 1.f / sum;
  __syncthreads();
  if (tid < 32) wsm[tid] = __expf(wsm[tid] - mx) * inv;
  __syncthreads();
#pragma unroll
  for (int rep = 0; rep < 2; ++rep) {
    int c = tid + 256 * rep;
    float acc = 0.f;
#pragma unroll
    for (int s = 0; s < 32; ++s) acc += wsm[s] * Hs[s * 512 + c];
    float hb = acc;
    float hv = fmaxf(Hv[(size_t)t * 512 + c], 0.f) * hb;
    float hs2 = fmaxf(hb, 0.f) * hv;
    Xcm[(size_t)t * 1024 + c] = f2bu(hv);
    Xcm[(size_t)t * 1024 + 512 + c] = f2bu(hs2);
  }
}

// ---------------------------------------------------------------------------
// Masked self-attention scores: P[i][j] = softmax_j>=i(tanh dot), bf16,
// zeros for j<i. Also copies Xsi[i][0:512] = hr_b[i].
// ---------------------------------------------------------------------------
__global__ __launch_bounds__(256)
void selfatt_score(const ushort* __restrict__ q2, const ushort* __restrict__ k2,
                   const float* __restrict__ siv, const ushort* __restrict__ hrb,
                   ushort* __restrict__ P, ushort* __restrict__ Xsi) {
  const int i = blockIdx.x, tid = threadIdx.x;
  const int lane = tid & 63, wave = tid >> 6;
  __shared__ float qsh[512], vsh[512], scr[512];
  qsh[tid] = b2f(q2[(size_t)i * 512 + tid]);
  qsh[256 + tid] = b2f(q2[(size_t)i * 512 + 256 + tid]);
  vsh[tid] = siv[tid];
  vsh[256 + tid] = siv[256 + tid];
  Xsi[(size_t)i * 1024 + tid] = hrb[(size_t)i * 512 + tid];
  Xsi[(size_t)i * 1024 + 256 + tid] = hrb[(size_t)i * 512 + 256 + tid];
  __syncthreads();
  for (int j = i + wave; j < 512; j += 4) {
    float p = 0.f;
#pragma unroll
    for (int r = 0; r < 8; ++r) {
      int c = lane + 64 * r;
      p += ftanh(qsh[c] + b2f(k2[(size_t)j * 512 + c])) * vsh[c];
    }
#pragma unroll
    for (int m = 32; m >= 1; m >>= 1) p += __shfl_xor(p, m, 64);
    if (lane == 0) scr[j] = p;
  }
  __syncthreads();
  float mx = -1e30f;
  for (int j = i; j < 512; ++j) mx = fmaxf(mx, scr[j]);
  float sum = 0.f;
  for (int j = i; j < 512; ++j) sum += __expf(scr[j] - mx);
  float inv = 1.f / sum;
  __syncthreads();
  for (int j = tid; j < 512; j += 256) {
    float p = (j >= i) ? __expf(scr[j] - mx) * inv : 0.f;
    P[(size_t)i * 512 + j] = f2bu(p);
  }
}

// ---------------------------------------------------------------------------
__global__ void ho_kernel(const float* __restrict__ Hs, float* __restrict__ ho) {
  int c = blockIdx.x * 256 + threadIdx.x;
  float a = 0.f;
#pragma unroll
  for (int s = 0; s < 32; ++s) a += Hs[s * 512 + c];
  ho[c] = a;
}

__global__ void cat_kernel(const ushort* __restrict__ hdb,
                           const float* __restrict__ ho,
                           ushort* __restrict__ cat) {
  int i = blockIdx.x, tid = threadIdx.x;
#pragma unroll
  for (int r = 0; r < 4; ++r) {
    int k = tid + 256 * r;
    cat[(size_t)i * 1024 + k] =
        (k < 512) ? hdb[(size_t)i * 512 + k] : f2bu(ho[k - 512]);
  }
}

__global__ __launch_bounds__(256)
void score_kernel(const float* __restrict__ tmp, const float* __restrict__ cpv,
                  float* __restrict__ out) {
  const int i = blockIdx.x, tid = threadIdx.x;
  float p = tmp[(size_t)i * 512 + tid] * cpv[tid] +
            tmp[(size_t)i * 512 + 256 + tid] * cpv[256 + tid];
#pragma unroll
  for (int m = 32; m >= 1; m >>= 1) p += __shfl_xor(p, m, 64);
  __shared__ float wsum[4];
  if ((tid & 63) == 0) wsum[tid >> 6] = p;
  __syncthreads();
  if (tid == 0) {
    out[i] = wsum[0] + wsum[1] + wsum[2] + wsum[3];
    out[497 + i] = (float)i;  // window_starts as float32
  }
}

// ---------------------------------------------------------------------------
extern "C" void kernel_launch(void* const* d_in, const int* in_sizes, int n_in,
                              void* d_out, int out_size, void* d_ws,
                              size_t ws_size, hipStream_t stream) {
  const float* video = (const float*)d_in[0];
  const int* text = (const int*)d_in[1];
  const float* vp_W = (const float*)d_in[2];
  const float* vp_b = (const float*)d_in[3];
  const float* vWih = (const float*)d_in[4];
  const float* vWhh = (const float*)d_in[5];
  const float* vbih = (const float*)d_in[6];
  const float* vbhh = (const float*)d_in[7];
  const float* emb = (const float*)d_in[8];
  const float* tp_W = (const float*)d_in[9];
  const float* tp_b = (const float*)d_in[10];
  const float* tWih = (const float*)d_in[11];
  const float* tWhh = (const float*)d_in[12];
  const float* tbih = (const float*)d_in[13];
  const float* tbhh = (const float*)d_in[14];
  const float* cmaWq = (const float*)d_in[15];
  const float* cmabq = (const float*)d_in[16];
  const float* cmaWk = (const float*)d_in[17];
  const float* cmabk = (const float*)d_in[18];
  const float* cmav = (const float*)d_in[19];
  const float* cmWih = (const float*)d_in[20];
  const float* cmWhh = (const float*)d_in[21];
  const float* cmbih = (const float*)d_in[22];
  const float* cmbhh = (const float*)d_in[23];
  const float* siWq = (const float*)d_in[24];
  const float* sibq = (const float*)d_in[25];
  const float* siWk = (const float*)d_in[26];
  const float* sibk = (const float*)d_in[27];
  const float* siv = (const float*)d_in[28];
  const float* sgWih = (const float*)d_in[29];
  const float* sgWhh = (const float*)d_in[30];
  const float* sgbih = (const float*)d_in[31];
  const float* sgbhh = (const float*)d_in[32];
  // d_in[33..35] dead (softmax over singleton axis == 1)
  const float* cpW1 = (const float*)d_in[36];
  const float* cpb1 = (const float*)d_in[37];
  const float* cpv = (const float*)d_in[38];
  float* out = (float*)d_out;

  float* ws = (float*)d_ws;
  size_t off = 0;
  auto alloc = [&](size_t n) {  // n in floats
    float* p = ws + off;
    off += (n + 3) & ~(size_t)3;
    return p;
  };
  auto allocU = [&](size_t n) { return (ushort*)alloc((n + 1) / 2); };
  // activations
  ushort* video_b = allocU(512 * 1024);
  ushort* x_emb_b = allocU(32 * 320);
  ushort* x_v_b = allocU(512 * 512);
  ushort* x_s_b = allocU(32 * 512);
  float* pre_v = alloc(2 * 512 * 768);
  float* pre_s = alloc(2 * 32 * 768);
  float* Hv = alloc(512 * 512);
  ushort* Hv_b = allocU(512 * 512);
  float* Hs = alloc(32 * 512);
  ushort* Hs_b = allocU(32 * 512);
  ushort* qv_b = allocU(512 * 512);
  ushort* ksb_b = allocU(32 * 512);
  ushort* Xcm_b = allocU(512 * 1024);
  float* pre_cm = alloc(512 * 1536);
  ushort* hr_b = allocU(512 * 512);
  ushort* hrT_b = allocU(512 * 512);
  ushort* q2_b = allocU(512 * 512);
  ushort* k2_b = allocU(512 * 512);
  ushort* P_b = allocU(512 * 512);
  ushort* Xsi_b = allocU(512 * 1024);
  float* pre_si = alloc(512 * 1536);
  ushort* hd_b = allocU(512 * 512);
  float* ho = alloc(512);
  ushort* cat_b = allocU(512 * 1024);
  float* tmpb = alloc(512 * 512);
  // scan weights (fp32 transposed)
  float* whhT_v = alloc(2 * 768 * 256);
  float* whhT_t = alloc(2 * 768 * 256);
  float* whhT_cm = alloc(1536 * 512);
  float* whhT_si = alloc(1536 * 512);
  // GEMM weights (bf16 transposed [N][Kp])
  ushort* vpW_T = allocU(512 * 1024);
  ushort* vWihT_f = allocU(768 * 512);
  ushort* vWihT_b = allocU(768 * 512);
  ushort* tpW_T = allocU(512 * 320);
  ushort* tWihT_f = allocU(768 * 512);
  ushort* tWihT_b = allocU(768 * 512);
  ushort* cmaWqT = allocU(512 * 512);
  ushort* cmaWkT = allocU(512 * 512);
  ushort* cmWihT = allocU(1536 * 1024);
  ushort* siWqT = allocU(512 * 512);
  ushort* siWkT = allocU(512 * 512);
  ushort* sgWihT = allocU(1536 * 1024);
  ushort* cpW1T = allocU(512 * 1024);
  // handoff word buffers, contiguous, zeroed per launch
  float* zero0 = ws + off;
  uint32_t* hw_vf = (uint32_t*)alloc(512 * 256);
  uint32_t* hw_vb = (uint32_t*)alloc(512 * 256);
  uint32_t* hw_tf = (uint32_t*)alloc(32 * 256);
  uint32_t* hw_tb = (uint32_t*)alloc(32 * 256);
  uint32_t* hw_cm = (uint32_t*)alloc(512 * 512);
  uint32_t* hw_si = (uint32_t*)alloc(512 * 512);
  size_t zero_bytes = ((ws + off) - zero0) * sizeof(float);
  hipMemsetAsync(zero0, 0, zero_bytes, stream);

  // ---- weight prep (one batched launch) ----
  PrepArgs pa{};
  int nd = 0;
  size_t total_tiles = 0;
  auto addT = [&](const float* src, ushort* db, float* df, int K, int N, int Kp) {
    pa.d[nd++] = TDesc{src, db, df, K, N, Kp};
    total_tiles += (size_t)((N + 31) / 32) * ((Kp + 31) / 32);
  };
  addT(vWhh, nullptr, whhT_v, 256, 768, 256);
  addT(vWhh + 196608, nullptr, whhT_v + 196608, 256, 768, 256);
  addT(tWhh, nullptr, whhT_t, 256, 768, 256);
  addT(tWhh + 196608, nullptr, whhT_t + 196608, 256, 768, 256);
  addT(cmWhh, nullptr, whhT_cm, 512, 1536, 512);
  addT(sgWhh, nullptr, whhT_si, 512, 1536, 512);
  addT(vp_W, vpW_T, nullptr, 1024, 512, 1024);
  addT(vWih, vWihT_f, nullptr, 512, 768, 512);
  addT(vWih + 393216, vWihT_b, nullptr, 512, 768, 512);
  addT(tp_W, tpW_T, nullptr, 300, 512, 320);
  addT(tWih, tWihT_f, nullptr, 512, 768, 512);
  addT(tWih + 393216, tWihT_b, nullptr, 512, 768, 512);
  addT(cmaWq, cmaWqT, nullptr, 512, 512, 512);
  addT(cmaWk, cmaWkT, nullptr, 512, 512, 512);
  addT(cmWih, cmWihT, nullptr, 1024, 1536, 1024);
  addT(siWq, siWqT, nullptr, 512, 512, 512);
  addT(siWk, siWkT, nullptr, 512, 512, 512);
  addT(sgWih, sgWihT, nullptr, 1024, 1536, 1024);
  addT(cpW1, cpW1T, nullptr, 1024, 512, 1024);
  pa.n = nd;
  prep_kernel<<<(int)total_tiles, 256, 0, stream>>>(pa);

  cast_kernel<<<512, 256, 0, stream>>>(video, video_b, 512 * 1024);
  emb_kernel<<<32, 256, 0, stream>>>(emb, text, x_emb_b);

  // projections + GRU input pre-activations (MFMA)
  mfma_gemm<<<dim3(8, 8), 256, 0, stream>>>(video_b, vpW_T, vp_b, x_v_b, 512, 512, 1024, 512, 2);
  mfma_gemm<<<dim3(12, 8), 256, 0, stream>>>(x_v_b, vWihT_f, vbih, pre_v, 512, 768, 512, 768, 0);
  mfma_gemm<<<dim3(12, 8), 256, 0, stream>>>(x_v_b, vWihT_b, vbih + 768, pre_v + 393216, 512, 768, 512, 768, 0);
  mfma_gemm<<<dim3(8, 1), 256, 0, stream>>>(x_emb_b, tpW_T, tp_b, x_s_b, 32, 512, 320, 512, 2);
  mfma_gemm<<<dim3(12, 1), 256, 0, stream>>>(x_s_b, tWihT_f, tbih, pre_s, 32, 768, 512, 768, 0);
  mfma_gemm<<<dim3(12, 1), 256, 0, stream>>>(x_s_b, tWihT_b, tbih + 768, pre_s + 24576, 32, 768, 512, 768, 0);

  // video + text BiGRU scans (4 instances x NB=8 blocks)
  ScanArgs a1{};
  a1.d[0] = ScanDesc{whhT_v, vbhh, pre_v, Hv, Hv_b, nullptr, hw_vf, 512, 0, 512, 0, 512, 0, 0};
  a1.d[1] = ScanDesc{whhT_v + 196608, vbhh + 768, pre_v + 393216, Hv, Hv_b, nullptr, hw_vb, 512, 1, 512, 256, 512, 256, 0};
  a1.d[2] = ScanDesc{whhT_t, tbhh, pre_s, Hs, Hs_b, nullptr, hw_tf, 32, 0, 512, 0, 512, 0, 0};
  a1.d[3] = ScanDesc{whhT_t + 196608, tbhh + 768, pre_s + 24576, Hs, Hs_b, nullptr, hw_tb, 32, 1, 512, 256, 512, 256, 0};
  scan_kernel<256, 8, 8><<<32, 256, 0, stream>>>(a1);

  // cross-modal attention
  mfma_gemm<<<dim3(8, 8), 256, 0, stream>>>(Hv_b, cmaWqT, cmabq, qv_b, 512, 512, 512, 512, 2);
  mfma_gemm<<<dim3(8, 1), 256, 0, stream>>>(Hs_b, cmaWkT, cmabk, ksb_b, 32, 512, 512, 512, 2);
  cma_kernel<<<512, 256, 0, stream>>>(qv_b, ksb_b, cmav, Hv, Hs, Xcm_b);
  mfma_gemm<<<dim3(24, 8), 256, 0, stream>>>(Xcm_b, cmWihT, cmbih, pre_cm, 512, 1536, 1024, 1536, 0);

  ScanArgs a2{};
  a2.d[0] = ScanDesc{whhT_cm, cmbhh, pre_cm, nullptr, hr_b, hrT_b, hw_cm, 512, 0, 0, 0, 512, 0, 512};
  scan_kernel<512, 32, 16><<<32, 256, 0, stream>>>(a2);

  // masked self-attention: scores+softmax (vector) then PV via MFMA
  mfma_gemm<<<dim3(8, 8), 256, 0, stream>>>(hr_b, siWqT, sibq, q2_b, 512, 512, 512, 512, 2);
  mfma_gemm<<<dim3(8, 8), 256, 0, stream>>>(hr_b, siWkT, sibk, k2_b, 512, 512, 512, 512, 2);
  selfatt_score<<<512, 256, 0, stream>>>(q2_b, k2_b, siv, hr_b, P_b, Xsi_b);
  mfma_gemm<<<dim3(8, 8), 256, 0, stream>>>(P_b, hrT_b, nullptr, Xsi_b + 512, 512, 512, 512, 1024, 2);
  mfma_gemm<<<dim3(24, 8), 256, 0, stream>>>(Xsi_b, sgWihT, sgbih, pre_si, 512, 1536, 1024, 1536, 0);

  ScanArgs a3{};
  a3.d[0] = ScanDesc{whhT_si, sgbhh, pre_si, nullptr, hd_b, nullptr, hw_si, 512, 0, 0, 0, 512, 0, 0};
  scan_kernel<512, 32, 16><<<32, 256, 0, stream>>>(a3);

  // scoring head
  ho_kernel<<<2, 256, 0, stream>>>(Hs, ho);
  cat_kernel<<<512, 256, 0, stream>>>(hd_b, ho, cat_b);
  mfma_gemm<<<dim3(8, 8), 256, 0, stream>>>(cat_b, cpW1T, cpb1, tmpb, 512, 512, 1024, 512, 1);
  score_kernel<<<497, 256, 0, stream>>>(tmpb, cpv, out);
}

// Round 8
// 3269.821 us; speedup vs baseline: 1.7894x; 1.2464x over previous
//
#include <hip/hip_runtime.h>
#include <hip/hip_bf16.h>
#include <cstdint>

#define DEV __device__ __forceinline__

typedef unsigned short ushort;
typedef __attribute__((ext_vector_type(8))) short bf16x8;
typedef __attribute__((ext_vector_type(4))) float f32x4;

DEV float fsig(float x) { return 1.f / (1.f + __expf(-x)); }
DEV float ftanh(float x) { return 1.f - 2.f / (1.f + __expf(2.f * x)); }
DEV ushort f2bu(float f) {
  __hip_bfloat16 h = __float2bfloat16(f);
  return *(ushort*)&h;
}
DEV float b2f(ushort u) { return __uint_as_float((uint32_t)u << 16); }

// DPP butterfly add within TPU-sized groups (no DS pipe).
template <int CTRL>
DEV float dpp_add(float v) {
  int x = __builtin_amdgcn_update_dpp(0, __float_as_int(v), CTRL, 0xF, 0xF, true);
  return v + __int_as_float(x);
}
template <int TPU>
DEV float dpp_reduce(float v) {
  v = dpp_add<0xB1>(v);
  v = dpp_add<0x4E>(v);
  if (TPU >= 8) v = dpp_add<0x141>(v);
  if (TPU >= 16) v = dpp_add<0x140>(v);
  return v;
}

// ---------------------------------------------------------------------------
// MFMA bf16 GEMM: C[M,N](ldc) = act(A[M,K]_bf16 @ (BT[N,K]_bf16)^T + bias)
// flags: 1 = tanh, 2 = bf16 output. N%64==0, K%32==0; M guarded. bias nullable.
// ---------------------------------------------------------------------------
__global__ __launch_bounds__(256)
void mfma_gemm(const ushort* __restrict__ A, const ushort* __restrict__ BT,
               const float* __restrict__ bias, void* __restrict__ Cout,
               int M, int N, int K, int ldc, int flags) {
  const int wave = threadIdx.x >> 6, lane = threadIdx.x & 63;
  const int m0 = blockIdx.y * 64 + wave * 16;
  const int n0 = blockIdx.x * 64;
  const int r = lane & 15, quad = lane >> 4;
  f32x4 acc[4] = {};
  const int arow = (m0 + r < M) ? (m0 + r) : 0;
  const ushort* ap = A + (size_t)arow * K + quad * 8;
  const ushort* bp = BT + (size_t)(n0 + r) * K + quad * 8;
#pragma unroll 2
  for (int k0 = 0; k0 < K; k0 += 32) {
    bf16x8 a = *(const bf16x8*)(ap + k0);
#pragma unroll
    for (int t = 0; t < 4; ++t) {
      bf16x8 b = *(const bf16x8*)(bp + (size_t)t * 16 * K + k0);
      acc[t] = __builtin_amdgcn_mfma_f32_16x16x32_bf16(a, b, acc[t], 0, 0, 0);
    }
  }
#pragma unroll
  for (int t = 0; t < 4; ++t) {
    const int col = n0 + t * 16 + r;
    const float bs = bias ? bias[col] : 0.f;
#pragma unroll
    for (int e = 0; e < 4; ++e) {
      const int row = m0 + quad * 4 + e;
      if (row < M) {
        float v = acc[t][e] + bs;
        if (flags & 1) v = ftanh(v);
        if (flags & 2)
          ((ushort*)Cout)[(size_t)row * ldc + col] = f2bu(v);
        else
          ((float*)Cout)[(size_t)row * ldc + col] = v;
      }
    }
  }
}

// ---------------------------------------------------------------------------
// Batched transpose(+pad) prep: src fp32 [K][N] -> dst [N][Kp] (bf16 or fp32)
// ---------------------------------------------------------------------------
struct TDesc {
  const float* src;
  ushort* db;
  float* df;
  int K, N, Kp;
};
struct PrepArgs {
  TDesc d[19];
  int n;
};

__global__ __launch_bounds__(256)
void prep_kernel(PrepArgs pa) {
  int rem = blockIdx.x;
  int di = 0;
  TDesc d{};
  for (; di < pa.n; ++di) {
    d = pa.d[di];
    int t = ((d.N + 31) >> 5) * ((d.Kp + 31) >> 5);
    if (rem < t) break;
    rem -= t;
  }
  if (di == pa.n) return;
  const int ntx = (d.Kp + 31) >> 5;
  const int ty = rem / ntx, tx = rem % ntx;
  __shared__ float t32[32][33];
  const int lx = threadIdx.x & 31, ly = threadIdx.x >> 5;
#pragma unroll
  for (int p = 0; p < 4; ++p) {
    int k = tx * 32 + ly + 8 * p;
    int n = ty * 32 + lx;
    t32[ly + 8 * p][lx] = (k < d.K && n < d.N) ? d.src[(size_t)k * d.N + n] : 0.f;
  }
  __syncthreads();
#pragma unroll
  for (int p = 0; p < 4; ++p) {
    int n = ty * 32 + ly + 8 * p;
    int k = tx * 32 + lx;
    if (n < d.N && k < d.Kp) {
      float v = t32[lx][ly + 8 * p];
      if (d.df)
        d.df[(size_t)n * d.Kp + k] = v;
      else
        d.db[(size_t)n * d.Kp + k] = f2bu(v);
    }
  }
}

__global__ void cast_kernel(const float* __restrict__ in,
                            ushort* __restrict__ out, int n) {
  int i = (blockIdx.x * 256 + threadIdx.x) * 4;
  if (i + 3 < n) {
    float4 v = *(const float4*)(in + i);
    out[i] = f2bu(v.x);
    out[i + 1] = f2bu(v.y);
    out[i + 2] = f2bu(v.z);
    out[i + 3] = f2bu(v.w);
  }
}

__global__ void emb_kernel(const float* __restrict__ emb,
                           const int* __restrict__ text,
                           ushort* __restrict__ xe) {
  int s = blockIdx.x;
  int row = text[s];
  for (int k = threadIdx.x; k < 320; k += 256)
    xe[s * 320 + k] = (k < 300) ? f2bu(emb[(size_t)row * 300 + k]) : (ushort)0;
}

// ---------------------------------------------------------------------------
// Persistent multi-block GRU scan, v8 = exact R3-measured-best protocol.
// Handoff: 64-bit (seq32<<32)|fp32bits pairs, relaxed agent-scope (LLC);
// poison 0xAAAAAAAA / memset-0 never equal a valid seq in [1,T].
// Wave 0 polls batched dwordx2 loads, stages LDS, releases LDS flag; other
// waves tight-spin on the flag (no s_sleep). Pre-row prefetched before the
// wait. Handoff pair stored before any mirror stores.
// ---------------------------------------------------------------------------
struct ScanDesc {
  const float* whhT;  // [3H][H]
  const float* bhh;   // [3H]
  const float* pre;   // [T][3H]
  float* out;         // optional fp32 out[pos*stride + off + unit]
  ushort* outb;       // optional bf16 mirror [pos*bstride + boff + unit]
  ushort* outbT;      // optional bf16 transposed mirror [unit*tld + pos]
  uint64_t* hb;       // [T][H] handoff pairs, zeroed per launch
  int T, dir, stride, off, bstride, boff, tld;
};
struct ScanArgs {
  ScanDesc d[4];
};

template <int H, int NB, int TPU>
__global__ __launch_bounds__(256, 1)
void scan_kernel(ScanArgs args) {
  constexpr int UPB = H / NB;   // units per block
  constexpr int B = UPB * TPU;  // block threads (256)
  constexpr int KS = H / TPU;   // k elems per thread (32)
  constexpr int PP = H / 64;    // pairs per wave0-lane per poll
  const ScanDesc d = args.d[blockIdx.x / NB];
  const int b = blockIdx.x % NB;
  const int tid = threadIdx.x;
  const int slice = tid % TPU, ug = tid / TPU;
  const int unit = b * UPB + ug;
  const int wid = tid >> 6, lane = tid & 63;

  float wr[KS], wz[KS], wn[KS];
#pragma unroll
  for (int j2 = 0; j2 < KS / 4; ++j2)
#pragma unroll
    for (int r = 0; r < 4; ++r) {
      int k = slice * 4 + 4 * TPU * j2 + r;
      int j = 4 * j2 + r;
      wr[j] = d.whhT[(size_t)(0 * H + unit) * H + k];
      wz[j] = d.whhT[(size_t)(1 * H + unit) * H + k];
      wn[j] = d.whhT[(size_t)(2 * H + unit) * H + k];
    }
  const float bhr = d.bhh[unit];
  const float bhz = d.bhh[H + unit];
  const float bhn = d.bhh[2 * H + unit];

  __shared__ float hsh[2][H];
  __shared__ int flag;
  for (int i = tid; i < H; i += B) hsh[0][i] = 0.f;
  if (tid == 0) flag = 0;  // step 0 pre-staged (h = 0)
  __syncthreads();

  const int T = d.T, dir = d.dir, stride = d.stride, off = d.off;
  uint64_t* __restrict__ hb = d.hb;

  for (int s = 0; s < T; ++s) {
    const int pos = dir ? (T - 1 - s) : s;
    const int cur = s & 1;
    // prefetch pre-row (h-independent) — overlaps the handoff wait
    const float* prow = d.pre + (size_t)pos * (3 * H);
    const float pir = prow[unit];
    const float piz = prow[H + unit];
    const float pin = prow[2 * H + unit];

    if (s > 0) {
      if (wid == 0) {
        const uint32_t want = (uint32_t)s;  // h(s-1) pairs carry seq = s
        const uint64_t* src = hb + (size_t)(s - 1) * H + lane;
        float hv[PP];
        for (;;) {
          uint64_t pv[PP];
          bool ok = true;
#pragma unroll
          for (int p = 0; p < PP; ++p)
            pv[p] = __hip_atomic_load(src + 64 * p, __ATOMIC_RELAXED,
                                      __HIP_MEMORY_SCOPE_AGENT);
#pragma unroll
          for (int p = 0; p < PP; ++p) {
            ok = ok && ((uint32_t)(pv[p] >> 32) == want);
            hv[p] = __uint_as_float((uint32_t)(pv[p] & 0xffffffffull));
          }
          if (__all(ok)) break;
        }
#pragma unroll
        for (int p = 0; p < PP; ++p) hsh[cur][lane + 64 * p] = hv[p];
        __hip_atomic_store(&flag, s, __ATOMIC_RELEASE,
                           __HIP_MEMORY_SCOPE_WORKGROUP);
      } else {
        while (__hip_atomic_load(&flag, __ATOMIC_ACQUIRE,
                                 __HIP_MEMORY_SCOPE_WORKGROUP) < s) {}
      }
    }

    float ar = 0.f, az = 0.f, an = 0.f;
    const float* hrow = hsh[cur];
#pragma unroll
    for (int j2 = 0; j2 < KS / 4; ++j2) {
      const float4 hv = *(const float4*)&hrow[slice * 4 + 4 * TPU * j2];
      const int j = 4 * j2;
      ar = fmaf(wr[j], hv.x, ar); ar = fmaf(wr[j + 1], hv.y, ar);
      ar = fmaf(wr[j + 2], hv.z, ar); ar = fmaf(wr[j + 3], hv.w, ar);
      az = fmaf(wz[j], hv.x, az); az = fmaf(wz[j + 1], hv.y, az);
      az = fmaf(wz[j + 2], hv.z, az); az = fmaf(wz[j + 3], hv.w, az);
      an = fmaf(wn[j], hv.x, an); an = fmaf(wn[j + 1], hv.y, an);
      an = fmaf(wn[j + 2], hv.z, an); an = fmaf(wn[j + 3], hv.w, an);
    }
    ar = dpp_reduce<TPU>(ar);
    az = dpp_reduce<TPU>(az);
    an = dpp_reduce<TPU>(an);

    if (slice == 0) {
      const float hp = hrow[unit];
      float r = fsig(pir + ar + bhr);
      float z = fsig(piz + az + bhz);
      float n = ftanh(pin + r * (an + bhn));
      float hn = (1.f - z) * n + z * hp;
      // handoff pair FIRST — it is the critical path
      uint64_t pk =
          ((uint64_t)(uint32_t)(s + 1) << 32) | (uint64_t)__float_as_uint(hn);
      __hip_atomic_store(&hb[(size_t)s * H + unit], pk, __ATOMIC_RELAXED,
                         __HIP_MEMORY_SCOPE_AGENT);
      const ushort hb16 = f2bu(hn);
      if (d.out) d.out[(size_t)pos * stride + off + unit] = hn;
      if (d.outb) d.outb[(size_t)pos * d.bstride + d.boff + unit] = hb16;
      if (d.outbT) d.outbT[(size_t)unit * d.tld + pos] = hb16;
    }
    // double-buffered hsh + seq-tagged handoff: no per-step barrier needed
  }
}

// ---------------------------------------------------------------------------
// Cross-modal attention (bf16 q/k in, bf16 Xcm out)
// ---------------------------------------------------------------------------
__global__ __launch_bounds__(256)
void cma_kernel(const ushort* __restrict__ qv, const ushort* __restrict__ ksm,
                const float* __restrict__ cmav, const float* __restrict__ Hv,
                const float* __restrict__ Hs, ushort* __restrict__ Xcm) {
  const int t = blockIdx.x, tid = threadIdx.x;
  const int lane = tid & 63, wave = tid >> 6;
  __shared__ float qsh[512], vsh[512], wsm[32];
  qsh[tid] = b2f(qv[t * 512 + tid]);
  qsh[256 + tid] = b2f(qv[t * 512 + 256 + tid]);
  vsh[tid] = cmav[tid];
  vsh[256 + tid] = cmav[256 + tid];
  __syncthreads();
  for (int s = wave; s < 32; s += 4) {
    float p = 0.f;
#pragma unroll
    for (int j = 0; j < 8; ++j) {
      int c = lane + 64 * j;
      p += ftanh(qsh[c] + b2f(ksm[s * 512 + c])) * vsh[c];
    }
#pragma unroll
    for (int m = 32; m >= 1; m >>= 1) p += __shfl_xor(p, m, 64);
    if (lane == 0) wsm[s] = p;
  }
  __syncthreads();
  float mx = -1e30f;
  for (int s = 0; s < 32; ++s) mx = fmaxf(mx, wsm[s]);
  float sum = 0.f;
  for (int s = 0; s < 32; ++s) sum += __expf(wsm[s] - mx);
  float inv = 1.f / sum;
  __syncthreads();
  if (tid < 32) wsm[tid] = __expf(wsm[tid] - mx) * inv;
  __syncthreads();
#pragma unroll
  for (int rep = 0; rep < 2; ++rep) {
    int c = tid + 256 * rep;
    float acc = 0.f;
#pragma unroll
    for (int s = 0; s < 32; ++s) acc += wsm[s] * Hs[s * 512 + c];
    float hb = acc;
    float hv = fmaxf(Hv[(size_t)t * 512 + c], 0.f) * hb;
    float hs2 = fmaxf(hb, 0.f) * hv;
    Xcm[(size_t)t * 1024 + c] = f2bu(hv);
    Xcm[(size_t)t * 1024 + 512 + c] = f2bu(hs2);
  }
}

// ---------------------------------------------------------------------------
// Masked self-attention scores: P[i][j] = softmax_j>=i(tanh dot), bf16,
// zeros for j<i. Also copies Xsi[i][0:512] = hr_b[i].
// ---------------------------------------------------------------------------
__global__ __launch_bounds__(256)
void selfatt_score(const ushort* __restrict__ q2, const ushort* __restrict__ k2,
                   const float* __restrict__ siv, const ushort* __restrict__ hrb,
                   ushort* __restrict__ P, ushort* __restrict__ Xsi) {
  const int i = blockIdx.x, tid = threadIdx.x;
  const int lane = tid & 63, wave = tid >> 6;
  __shared__ float qsh[512], vsh[512], scr[512];
  qsh[tid] = b2f(q2[(size_t)i * 512 + tid]);
  qsh[256 + tid] = b2f(q2[(size_t)i * 512 + 256 + tid]);
  vsh[tid] = siv[tid];
  vsh[256 + tid] = siv[256 + tid];
  Xsi[(size_t)i * 1024 + tid] = hrb[(size_t)i * 512 + tid];
  Xsi[(size_t)i * 1024 + 256 + tid] = hrb[(size_t)i * 512 + 256 + tid];
  __syncthreads();
  for (int j = i + wave; j < 512; j += 4) {
    float p = 0.f;
#pragma unroll
    for (int r = 0; r < 8; ++r) {
      int c = lane + 64 * r;
      p += ftanh(qsh[c] + b2f(k2[(size_t)j * 512 + c])) * vsh[c];
    }
#pragma unroll
    for (int m = 32; m >= 1; m >>= 1) p += __shfl_xor(p, m, 64);
    if (lane == 0) scr[j] = p;
  }
  __syncthreads();
  float mx = -1e30f;
  for (int j = i; j < 512; ++j) mx = fmaxf(mx, scr[j]);
  float sum = 0.f;
  for (int j = i; j < 512; ++j) sum += __expf(scr[j] - mx);
  float inv = 1.f / sum;
  __syncthreads();
  for (int j = tid; j < 512; j += 256) {
    float p = (j >= i) ? __expf(scr[j] - mx) * inv : 0.f;
    P[(size_t)i * 512 + j] = f2bu(p);
  }
}

// ---------------------------------------------------------------------------
__global__ void ho_kernel(const float* __restrict__ Hs, float* __restrict__ ho) {
  int c = blockIdx.x * 256 + threadIdx.x;
  float a = 0.f;
#pragma unroll
  for (int s = 0; s < 32; ++s) a += Hs[s * 512 + c];
  ho[c] = a;
}

__global__ void cat_kernel(const ushort* __restrict__ hdb,
                           const float* __restrict__ ho,
                           ushort* __restrict__ cat) {
  int i = blockIdx.x, tid = threadIdx.x;
#pragma unroll
  for (int r = 0; r < 4; ++r) {
    int k = tid + 256 * r;
    cat[(size_t)i * 1024 + k] =
        (k < 512) ? hdb[(size_t)i * 512 + k] : f2bu(ho[k - 512]);
  }
}

__global__ __launch_bounds__(256)
void score_kernel(const float* __restrict__ tmp, const float* __restrict__ cpv,
                  float* __restrict__ out) {
  const int i = blockIdx.x, tid = threadIdx.x;
  float p = tmp[(size_t)i * 512 + tid] * cpv[tid] +
            tmp[(size_t)i * 512 + 256 + tid] * cpv[256 + tid];
#pragma unroll
  for (int m = 32; m >= 1; m >>= 1) p += __shfl_xor(p, m, 64);
  __shared__ float wsum[4];
  if ((tid & 63) == 0) wsum[tid >> 6] = p;
  __syncthreads();
  if (tid == 0) {
    out[i] = wsum[0] + wsum[1] + wsum[2] + wsum[3];
    out[497 + i] = (float)i;  // window_starts as float32
  }
}

// ---------------------------------------------------------------------------
extern "C" void kernel_launch(void* const* d_in, const int* in_sizes, int n_in,
                              void* d_out, int out_size, void* d_ws,
                              size_t ws_size, hipStream_t stream) {
  const float* video = (const float*)d_in[0];
  const int* text = (const int*)d_in[1];
  const float* vp_W = (const float*)d_in[2];
  const float* vp_b = (const float*)d_in[3];
  const float* vWih = (const float*)d_in[4];
  const float* vWhh = (const float*)d_in[5];
  const float* vbih = (const float*)d_in[6];
  const float* vbhh = (const float*)d_in[7];
  const float* emb = (const float*)d_in[8];
  const float* tp_W = (const float*)d_in[9];
  const float* tp_b = (const float*)d_in[10];
  const float* tWih = (const float*)d_in[11];
  const float* tWhh = (const float*)d_in[12];
  const float* tbih = (const float*)d_in[13];
  const float* tbhh = (const float*)d_in[14];
  const float* cmaWq = (const float*)d_in[15];
  const float* cmabq = (const float*)d_in[16];
  const float* cmaWk = (const float*)d_in[17];
  const float* cmabk = (const float*)d_in[18];
  const float* cmav = (const float*)d_in[19];
  const float* cmWih = (const float*)d_in[20];
  const float* cmWhh = (const float*)d_in[21];
  const float* cmbih = (const float*)d_in[22];
  const float* cmbhh = (const float*)d_in[23];
  const float* siWq = (const float*)d_in[24];
  const float* sibq = (const float*)d_in[25];
  const float* siWk = (const float*)d_in[26];
  const float* sibk = (const float*)d_in[27];
  const float* siv = (const float*)d_in[28];
  const float* sgWih = (const float*)d_in[29];
  const float* sgWhh = (const float*)d_in[30];
  const float* sgbih = (const float*)d_in[31];
  const float* sgbhh = (const float*)d_in[32];
  // d_in[33..35] dead (softmax over singleton axis == 1)
  const float* cpW1 = (const float*)d_in[36];
  const float* cpb1 = (const float*)d_in[37];
  const float* cpv = (const float*)d_in[38];
  float* out = (float*)d_out;

  float* ws = (float*)d_ws;
  size_t off = 0;
  auto alloc = [&](size_t n) {  // n in floats
    float* p = ws + off;
    off += (n + 3) & ~(size_t)3;
    return p;
  };
  auto allocU = [&](size_t n) { return (ushort*)alloc((n + 1) / 2); };
  // activations
  ushort* video_b = allocU(512 * 1024);
  ushort* x_emb_b = allocU(32 * 320);
  ushort* x_v_b = allocU(512 * 512);
  ushort* x_s_b = allocU(32 * 512);
  float* pre_v = alloc(2 * 512 * 768);
  float* pre_s = alloc(2 * 32 * 768);
  float* Hv = alloc(512 * 512);
  ushort* Hv_b = allocU(512 * 512);
  float* Hs = alloc(32 * 512);
  ushort* Hs_b = allocU(32 * 512);
  ushort* qv_b = allocU(512 * 512);
  ushort* ksb_b = allocU(32 * 512);
  ushort* Xcm_b = allocU(512 * 1024);
  float* pre_cm = alloc(512 * 1536);
  ushort* hr_b = allocU(512 * 512);
  ushort* hrT_b = allocU(512 * 512);
  ushort* q2_b = allocU(512 * 512);
  ushort* k2_b = allocU(512 * 512);
  ushort* P_b = allocU(512 * 512);
  ushort* Xsi_b = allocU(512 * 1024);
  float* pre_si = alloc(512 * 1536);
  ushort* hd_b = allocU(512 * 512);
  float* ho = alloc(512);
  ushort* cat_b = allocU(512 * 1024);
  float* tmpb = alloc(512 * 512);
  // scan weights (fp32 transposed)
  float* whhT_v = alloc(2 * 768 * 256);
  float* whhT_t = alloc(2 * 768 * 256);
  float* whhT_cm = alloc(1536 * 512);
  float* whhT_si = alloc(1536 * 512);
  // GEMM weights (bf16 transposed [N][Kp])
  ushort* vpW_T = allocU(512 * 1024);
  ushort* vWihT_f = allocU(768 * 512);
  ushort* vWihT_b = allocU(768 * 512);
  ushort* tpW_T = allocU(512 * 320);
  ushort* tWihT_f = allocU(768 * 512);
  ushort* tWihT_b = allocU(768 * 512);
  ushort* cmaWqT = allocU(512 * 512);
  ushort* cmaWkT = allocU(512 * 512);
  ushort* cmWihT = allocU(1536 * 1024);
  ushort* siWqT = allocU(512 * 512);
  ushort* siWkT = allocU(512 * 512);
  ushort* sgWihT = allocU(1536 * 1024);
  ushort* cpW1T = allocU(512 * 1024);
  // handoff pair buffers (uint64 each), contiguous, zeroed per launch
  float* zero0 = ws + off;
  uint64_t* hb_vf = (uint64_t*)alloc(512 * 256 * 2);
  uint64_t* hb_vb = (uint64_t*)alloc(512 * 256 * 2);
  uint64_t* hb_tf = (uint64_t*)alloc(32 * 256 * 2);
  uint64_t* hb_tb = (uint64_t*)alloc(32 * 256 * 2);
  uint64_t* hb_cm = (uint64_t*)alloc(512 * 512 * 2);
  uint64_t* hb_si = (uint64_t*)alloc(512 * 512 * 2);
  size_t zero_bytes = ((ws + off) - zero0) * sizeof(float);
  hipMemsetAsync(zero0, 0, zero_bytes, stream);

  // ---- weight prep (one batched launch) ----
  PrepArgs pa{};
  int nd = 0;
  size_t total_tiles = 0;
  auto addT = [&](const float* src, ushort* db, float* df, int K, int N, int Kp) {
    pa.d[nd++] = TDesc{src, db, df, K, N, Kp};
    total_tiles += (size_t)((N + 31) / 32) * ((Kp + 31) / 32);
  };
  addT(vWhh, nullptr, whhT_v, 256, 768, 256);
  addT(vWhh + 196608, nullptr, whhT_v + 196608, 256, 768, 256);
  addT(tWhh, nullptr, whhT_t, 256, 768, 256);
  addT(tWhh + 196608, nullptr, whhT_t + 196608, 256, 768, 256);
  addT(cmWhh, nullptr, whhT_cm, 512, 1536, 512);
  addT(sgWhh, nullptr, whhT_si, 512, 1536, 512);
  addT(vp_W, vpW_T, nullptr, 1024, 512, 1024);
  addT(vWih, vWihT_f, nullptr, 512, 768, 512);
  addT(vWih + 393216, vWihT_b, nullptr, 512, 768, 512);
  addT(tp_W, tpW_T, nullptr, 300, 512, 320);
  addT(tWih, tWihT_f, nullptr, 512, 768, 512);
  addT(tWih + 393216, tWihT_b, nullptr, 512, 768, 512);
  addT(cmaWq, cmaWqT, nullptr, 512, 512, 512);
  addT(cmaWk, cmaWkT, nullptr, 512, 512, 512);
  addT(cmWih, cmWihT, nullptr, 1024, 1536, 1024);
  addT(siWq, siWqT, nullptr, 512, 512, 512);
  addT(siWk, siWkT, nullptr, 512, 512, 512);
  addT(sgWih, sgWihT, nullptr, 1024, 1536, 1024);
  addT(cpW1, cpW1T, nullptr, 1024, 512, 1024);
  pa.n = nd;
  prep_kernel<<<(int)total_tiles, 256, 0, stream>>>(pa);

  cast_kernel<<<512, 256, 0, stream>>>(video, video_b, 512 * 1024);
  emb_kernel<<<32, 256, 0, stream>>>(emb, text, x_emb_b);

  // projections + GRU input pre-activations (MFMA)
  mfma_gemm<<<dim3(8, 8), 256, 0, stream>>>(video_b, vpW_T, vp_b, x_v_b, 512, 512, 1024, 512, 2);
  mfma_gemm<<<dim3(12, 8), 256, 0, stream>>>(x_v_b, vWihT_f, vbih, pre_v, 512, 768, 512, 768, 0);
  mfma_gemm<<<dim3(12, 8), 256, 0, stream>>>(x_v_b, vWihT_b, vbih + 768, pre_v + 393216, 512, 768, 512, 768, 0);
  mfma_gemm<<<dim3(8, 1), 256, 0, stream>>>(x_emb_b, tpW_T, tp_b, x_s_b, 32, 512, 320, 512, 2);
  mfma_gemm<<<dim3(12, 1), 256, 0, stream>>>(x_s_b, tWihT_f, tbih, pre_s, 32, 768, 512, 768, 0);
  mfma_gemm<<<dim3(12, 1), 256, 0, stream>>>(x_s_b, tWihT_b, tbih + 768, pre_s + 24576, 32, 768, 512, 768, 0);

  // video + text BiGRU scans (4 instances x NB=8 blocks)
  ScanArgs a1{};
  a1.d[0] = ScanDesc{whhT_v, vbhh, pre_v, Hv, Hv_b, nullptr, hb_vf, 512, 0, 512, 0, 512, 0, 0};
  a1.d[1] = ScanDesc{whhT_v + 196608, vbhh + 768, pre_v + 393216, Hv, Hv_b, nullptr, hb_vb, 512, 1, 512, 256, 512, 256, 0};
  a1.d[2] = ScanDesc{whhT_t, tbhh, pre_s, Hs, Hs_b, nullptr, hb_tf, 32, 0, 512, 0, 512, 0, 0};
  a1.d[3] = ScanDesc{whhT_t + 196608, tbhh + 768, pre_s + 24576, Hs, Hs_b, nullptr, hb_tb, 32, 1, 512, 256, 512, 256, 0};
  scan_kernel<256, 8, 8><<<32, 256, 0, stream>>>(a1);

  // cross-modal attention
  mfma_gemm<<<dim3(8, 8), 256, 0, stream>>>(Hv_b, cmaWqT, cmabq, qv_b, 512, 512, 512, 512, 2);
  mfma_gemm<<<dim3(8, 1), 256, 0, stream>>>(Hs_b, cmaWkT, cmabk, ksb_b, 32, 512, 512, 512, 2);
  cma_kernel<<<512, 256, 0, stream>>>(qv_b, ksb_b, cmav, Hv, Hs, Xcm_b);
  mfma_gemm<<<dim3(24, 8), 256, 0, stream>>>(Xcm_b, cmWihT, cmbih, pre_cm, 512, 1536, 1024, 1536, 0);

  ScanArgs a2{};
  a2.d[0] = ScanDesc{whhT_cm, cmbhh, pre_cm, nullptr, hr_b, hrT_b, hb_cm, 512, 0, 0, 0, 512, 0, 512};
  scan_kernel<512, 32, 16><<<32, 256, 0, stream>>>(a2);

  // masked self-attention: scores+softmax (vector) then PV via MFMA
  mfma_gemm<<<dim3(8, 8), 256, 0, stream>>>(hr_b, siWqT, sibq, q2_b, 512, 512, 512, 512, 2);
  mfma_gemm<<<dim3(8, 8), 256, 0, stream>>>(hr_b, siWkT, sibk, k2_b, 512, 512, 512, 512, 2);
  selfatt_score<<<512, 256, 0, stream>>>(q2_b, k2_b, siv, hr_b, P_b, Xsi_b);
  mfma_gemm<<<dim3(8, 8), 256, 0, stream>>>(P_b, hrT_b, nullptr, Xsi_b + 512, 512, 512, 512, 1024, 2);
  mfma_gemm<<<dim3(24, 8), 256, 0, stream>>>(Xsi_b, sgWihT, sgbih, pre_si, 512, 1536, 1024, 1536, 0);

  ScanArgs a3{};
  a3.d[0] = ScanDesc{whhT_si, sgbhh, pre_si, nullptr, hd_b, nullptr, hb_si, 512, 0, 0, 0, 512, 0, 0};
  scan_kernel<512, 32, 16><<<32, 256, 0, stream>>>(a3);

  // scoring head
  ho_kernel<<<2, 256, 0, stream>>>(Hs, ho);
  cat_kernel<<<512, 256, 0, stream>>>(hd_b, ho, cat_b);
  mfma_gemm<<<dim3(8, 8), 256, 0, stream>>>(cat_b, cpW1T, cpb1, tmpb, 512, 512, 1024, 512, 1);
  score_kernel<<<497, 256, 0, stream>>>(tmpb, cpv, out);
}